// Round 7
// baseline (233.217 us; speedup 1.0000x reference)
//
#include <hip/hip_runtime.h>

#define EMB   256
#define NCLS  100
#define NB    64
#define NS    128
#define NL    64

// ---------------------------------------------------------------------------
// Kernel 1: sents[sid][e] = (1/NL) * sum_l emb[tok[sid,l]][e]
// One WAVE per sentence. Lane covers the 256-float row as float4 (64 lanes x
// 16B = 1KB coalesced per row). Tokens broadcast via v_readlane; loads
// batched 8-deep for MLP. AT THE ~6 TB/s L2-MISS/FABRIC WALL (88 us floor:
// 536 MB demand / 88 us = 6.1 TB/s; duration identical whether served from
// HBM (FETCH=253MB) or L3 (FETCH=8MB) — do not touch).
// ---------------------------------------------------------------------------
__global__ __launch_bounds__(256) void k_gather_mean(
    const int* __restrict__ tok, const float* __restrict__ emb,
    float* __restrict__ sents)
{
    const int w    = threadIdx.x >> 6;
    const int lane = threadIdx.x & 63;
    const int sid  = blockIdx.x * 4 + w;          // grid.x = NB*NS/4 = 2048

    const int mytok = tok[(size_t)sid * NL + lane];   // lane l holds token l

    float4 acc = make_float4(0.f, 0.f, 0.f, 0.f);
    for (int i = 0; i < NL; i += 8) {
        float4 v[8];
        #pragma unroll
        for (int j = 0; j < 8; ++j) {
            const int tk = __builtin_amdgcn_readlane(mytok, i + j);  // SGPR
            v[j] = reinterpret_cast<const float4*>(emb + (size_t)tk * EMB)[lane];
        }
        #pragma unroll
        for (int j = 0; j < 8; ++j) {
            acc.x += v[j].x; acc.y += v[j].y; acc.z += v[j].z; acc.w += v[j].w;
        }
    }
    const float s = 1.0f / NL;
    float4 r; r.x = acc.x * s; r.y = acc.y * s; r.z = acc.z * s; r.w = acc.w * s;
    reinterpret_cast<float4*>(sents + (size_t)sid * EMB)[lane] = r;
}

__device__ __forceinline__ float dot4(float4 a, float4 b) {
    return a.x * b.x + a.y * b.y + a.z * b.z + a.w * b.w;
}

// ---------------------------------------------------------------------------
// Kernel 2 v5: logits[b,c] = sum_s softmax_s(ce[c].s_bs) * (mw[c].s_bs) + b[c]
// v4 was LDS-READ-PIPE-BOUND: wave=class meant each wave re-read the whole
// 16KB chunk per ec (tile read 4x/block, ~640KB LDS traffic, ~20us/CU).
// v5: waves partition the E dimension — wave w owns an 8-float slice of each
// 32-float chunk (WAVE-UNIFORM -> weight loads stay scalar), lane owns the
// sentence pair {lane, lane+64}, each wave accumulates partials for ALL 4
// block-classes. Tile read EXACTLY ONCE per block (256KB LDS traffic incl.
// writes ~8us, overlapped with 5.3us VALU). Epilogue: cross-wave e-partial
// sum via LDS (reusing stile -> LDS stays 18.4KB, 8 blocks/CU), then the
// proven wave-local softmax with wave=class. Grid (64,25) = 1600 blocks,
// 6400 waves = 78% occupancy cap.
// ---------------------------------------------------------------------------
#define CB    4
#define EC    32           // e-chunk floats
#define SROW  36           // LDS row stride: 16B-slot bank = 9*lane+c -> 2-way (free)

__global__ __launch_bounds__(256) void k_attn_logits5(
    const float* __restrict__ sents, const float* __restrict__ ce,
    const float* __restrict__ mw,    const float* __restrict__ bias,
    float* __restrict__ out)
{
    const int b    = blockIdx.x;
    const int c0   = blockIdx.y * CB;
    const int t    = threadIdx.x;
    const int wv   = __builtin_amdgcn_readfirstlane(t >> 6);  // wave 0..3
    const int lane = t & 63;
    const int w8   = wv * 8;       // this wave's float offset inside each chunk

    __shared__ float stile[NS][SROW];            // 18432 B

    float sc0[CB], sc1[CB], tv0[CB], tv1[CB];
    #pragma unroll
    for (int c = 0; c < CB; ++c) { sc0[c] = sc1[c] = tv0[c] = tv1[c] = 0.f; }

    const float* sbase = sents + (size_t)b * NS * EMB;

    for (int ec = 0; ec < EMB / EC; ++ec) {
        __syncthreads();                         // protect previous chunk reads
        // stage 128 x 32 floats: 1024 float4 over 256 threads, coalesced
        {
            int i = t;
            #pragma unroll
            for (int r = 0; r < 4; ++r, i += 256) {
                const int s = i >> 3, e4 = i & 7;
                *reinterpret_cast<float4*>(&stile[s][e4 * 4]) =
                    reinterpret_cast<const float4*>(
                        sbase + (size_t)s * EMB + ec * EC)[e4];
            }
        }
        __syncthreads();

        #pragma unroll
        for (int k4 = 0; k4 < 2; ++k4) {         // 2 float4 steps = 8 floats
            const float4 s0 = *reinterpret_cast<const float4*>(&stile[lane][w8 + k4 * 4]);
            const float4 s1 = *reinterpret_cast<const float4*>(&stile[lane + 64][w8 + k4 * 4]);
            #pragma unroll
            for (int c = 0; c < CB; ++c) {
                const size_t wo = (size_t)(c0 + c) * EMB + ec * EC + w8 + k4 * 4;
                const float4 w4 = *reinterpret_cast<const float4*>(ce + wo);
                const float4 m4 = *reinterpret_cast<const float4*>(mw + wo);
                sc0[c] += dot4(s0, w4); sc1[c] += dot4(s1, w4);
                tv0[c] += dot4(s0, m4); tv1[c] += dot4(s1, m4);
            }
        }
    }

    // Cross-wave e-partial reduction through LDS (reuse stile: 4096 <= 4608 floats).
    __syncthreads();                             // done reading stile as tile
    float* red = &stile[0][0];                   // red[(w*CB+c)*2+q][s], q=0 sc,1 tv
    #pragma unroll
    for (int c = 0; c < CB; ++c) {
        red[((wv * CB + c) * 2 + 0) * NS + lane]      = sc0[c];
        red[((wv * CB + c) * 2 + 0) * NS + lane + 64] = sc1[c];
        red[((wv * CB + c) * 2 + 1) * NS + lane]      = tv0[c];
        red[((wv * CB + c) * 2 + 1) * NS + lane + 64] = tv1[c];
    }
    __syncthreads();

    // Wave wv finalizes class wv (CB == 4 waves). Sum the 4 e-slice partials.
    const int c = wv;
    float a0 = 0.f, a1 = 0.f, q0 = 0.f, q1 = 0.f;
    #pragma unroll
    for (int w2 = 0; w2 < 4; ++w2) {
        a0 += red[((w2 * CB + c) * 2 + 0) * NS + lane];
        a1 += red[((w2 * CB + c) * 2 + 0) * NS + lane + 64];
        q0 += red[((w2 * CB + c) * 2 + 1) * NS + lane];
        q1 += red[((w2 * CB + c) * 2 + 1) * NS + lane + 64];
    }

    // Wave-local softmax-weighted sum (lane covers sentences lane, lane+64).
    float m = fmaxf(a0, a1);
    #pragma unroll
    for (int d = 1; d < 64; d <<= 1) m = fmaxf(m, __shfl_xor(m, d));
    const float p0 = __expf(a0 - m), p1 = __expf(a1 - m);
    float sp = p0 + p1;
    float st = p0 * q0 + p1 * q1;
    #pragma unroll
    for (int d = 1; d < 64; d <<= 1) {
        sp += __shfl_xor(sp, d);
        st += __shfl_xor(st, d);
    }
    if (lane == 0)
        out[(size_t)b * NCLS + c0 + c] = st / sp + bias[c0 + c];
}

extern "C" void kernel_launch(void* const* d_in, const int* in_sizes, int n_in,
                              void* d_out, int out_size, void* d_ws, size_t ws_size,
                              hipStream_t stream)
{
    const int*   tok  = (const int*)  d_in[0];   // (B,S,L) int32
    const float* emb  = (const float*)d_in[1];   // (VOCAB, EMB)
    const float* ce   = (const float*)d_in[2];   // (NCLS, EMB)
    const float* mw   = (const float*)d_in[3];   // (NCLS, EMB)
    const float* bias = (const float*)d_in[4];   // (NCLS, 1)
    float* out   = (float*)d_out;                // (B, NCLS)
    float* sents = (float*)d_ws;                 // NB*NS*EMB floats = 8 MB

    k_gather_mean<<<NB * NS / 4, 256, 0, stream>>>(tok, emb, sents);
    k_attn_logits5<<<dim3(NB, NCLS / CB), 256, 0, stream>>>(sents, ce, mw, bias, out);
}